// Round 11
// baseline (89.573 us; speedup 1.0000x reference)
//
#include <hip/hip_runtime.h>
#include <hip/hip_bf16.h>

// Shapes
#define BB 16
#define PP 64
#define NN 4096
#define DD 768
#define TT 8       // tokens per tile
#define NTILE 32   // tiles per 256-token chunk
#define VROW 772   // padded LDS row stride (f32): 772 % 32 == 4 -> bank-spread rows

typedef __attribute__((ext_vector_type(4))) float f32x4;
typedef __attribute__((ext_vector_type(8))) __bf16 bf16x8;
typedef __attribute__((ext_vector_type(4))) short s16x4;
typedef __attribute__((ext_vector_type(4))) _Float16 f16x4;

#if __has_builtin(__builtin_amdgcn_mfma_f32_16x16x16bf16_1k)
#define HAVE_K16 1
#define PSTRIDE 20
#else
#define HAVE_K16 0
#define PSTRIDE 40
#endif

__device__ __forceinline__ f32x4 mfma16(bf16x8 a, bf16x8 b, f32x4 c) {
    return __builtin_amdgcn_mfma_f32_16x16x32_bf16(a, b, c, 0, 0, 0);
}

__device__ __forceinline__ void gl_lds(const float* g, float* l) {
    __builtin_amdgcn_global_load_lds(
        (const __attribute__((address_space(1))) void*)g,
        (__attribute__((address_space(3))) void*)l, 16, 0, 0);
}

__device__ __forceinline__ short bf2s(float f) {
    __bf16 h = (__bf16)f;
    return *(short*)&h;
}

#define S_WAITCNT_VM(N) asm volatile("s_waitcnt vmcnt(" #N ")" ::: "memory")
#define BARRIER() do { __builtin_amdgcn_s_barrier(); asm volatile("" ::: "memory"); } while (0)
// LDS-only barrier: drains ds ops, NOT vmcnt (DMA prefetch stays in flight).
#define LDS_BARRIER() do { asm volatile("s_waitcnt lgkmcnt(0)" ::: "memory"); \
                           __builtin_amdgcn_s_barrier(); \
                           __builtin_amdgcn_sched_barrier(0); } while (0)

// LDS layout (bytes):
//   [0,      98816)  vstage[4][8][772] f32   (ring-4, window = 3 tiles ahead)
//   [98816, 119296)  lpf[8][64][10] f32      (QK^T kd-slice partials)
//   [119296,124416)  pbuf[64][PSTRIDE] bf16  (P tile; k>=TT zeroed)
//   [124416,125184)  mrun/lrun/rsc [64] f32 each
#define SM_BYTES 125184

// ---------------------------------------------------------------------------
// Flash: per (b, 256-token chunk), stream 32 tiles of 8 tokens x 768 d (f32)
// through a 4-slot LDS ring ONCE; per tile: QK^T -> online softmax -> PV into
// reg-resident O. grid 256 = 16 b x 16 chunks; block 512 (8 waves).
// ---------------------------------------------------------------------------
__global__ __launch_bounds__(512, 2) void k_flash(const float* __restrict__ x,
                                                  const float* __restrict__ q,
                                                  float* __restrict__ statm,
                                                  float* __restrict__ statl,
                                                  _Float16* __restrict__ part) {
    const int b  = blockIdx.x >> 4;
    const int sp = blockIdx.x & 15;
    const int n0 = sp * 256;

    __shared__ __align__(16) char smem[SM_BYTES];
    float*  vst  = (float*)smem;
    float*  lpf  = (float*)(smem + 98816);
    __bf16* pbuf = (__bf16*)(smem + 119296);
    float*  mrun = (float*)(smem + 124416);
    float*  lrun = (float*)(smem + 124672);
    float*  rsc  = (float*)(smem + 124928);

    const int t = threadIdx.x;
    const int w = t >> 6, lane = t & 63;
    const int l15 = lane & 15, hi = lane >> 4;

    const size_t xbase = (size_t)b * NN + n0;
    const size_t qbase = (size_t)b * PP;

    // ---- Q-fragment preload: wave w owns kd-slice [w*96, w*96+96) ----
    bf16x8 qf[4][3];
    #pragma unroll
    for (int am = 0; am < 4; ++am)
        #pragma unroll
        for (int s = 0; s < 3; ++s) {
            const size_t off = (qbase + am * 16 + l15) * DD + w * 96 + s * 32 + hi * 8;
            const float4 a = *(const float4*)&q[off];
            const float4 c = *(const float4*)&q[off + 4];
            qf[am][s] = (bf16x8){(__bf16)a.x, (__bf16)a.y, (__bf16)a.z, (__bf16)a.w,
                                 (__bf16)c.x, (__bf16)c.y, (__bf16)c.z, (__bf16)c.w};
        }

    // zero P pad region (k >= TT multiplies real data; must be true zero)
    for (int i = t; i < 64 * PSTRIDE / 2; i += 512) ((unsigned*)pbuf)[i] = 0;
    if (t < 64) { mrun[t] = -1e30f; lrun[t] = 0.f; }

    // O accumulator: wave w owns d-slice [w*96, w*96+96): 4 p-frags x 6 d-frags.
    f32x4 O[4][6] = {};

    // Staging: 24 issues/block (3/wave); issue idx covers row idx/3, third idx%3.
    // Fully linear source (1 KB bursts) and dest.
#define STAGE(bufi, tile) do {                                                \
        float* vb_ = vst + (bufi) * (TT * VROW);                              \
        _Pragma("unroll")                                                     \
        for (int i_ = 0; i_ < 3; ++i_) {                                      \
            const int idx_ = w * 3 + i_;                                      \
            const int r_ = idx_ / 3, c_ = idx_ % 3;                           \
            gl_lds(&x[(xbase + (size_t)(tile) * TT + r_) * DD + c_ * 256 + lane * 4], \
                   vb_ + r_ * VROW + c_ * 256);                               \
        }                                                                     \
    } while (0)

    STAGE(0, 0);
    STAGE(1, 1);
    STAGE(2, 2);

    const float scale = 0.036084391824351615f;  // 768^-0.5
    const int p_  = t >> 3;      // softmax row (0..63)
    const int np_ = t & 7;       // softmax token (0..7)

    for (int tile = 0; tile < NTILE; ++tile) {
        if (tile < NTILE - 3)      { STAGE((tile + 3) & 3, tile + 3); S_WAITCNT_VM(9); }
        else if (tile == NTILE - 3) { S_WAITCNT_VM(6); }
        else if (tile == NTILE - 2) { S_WAITCNT_VM(3); }
        else                        { S_WAITCNT_VM(0); }
        BARRIER();
        const float* vb = vst + (tile & 3) * (TT * VROW);

        // ---- QK^T: wave w: kd in {w*96, +32, +64}, all 4 p-frags ----
        // B-frag rows l15>=8 duplicate rows 0..7 (finite; cols 8..15 unused).
        f32x4 acc[4] = {};
        #pragma unroll
        for (int s = 0; s < 3; ++s) {
            const int g0 = w * 24 + s * 8 + hi * 2;
            const float* kp = vb + (l15 & 7) * VROW + g0 * 4;
            const f32x4 lo = *(const f32x4*)kp;
            const f32x4 hg = *(const f32x4*)(kp + 4);
            const bf16x8 kf = {(__bf16)lo[0], (__bf16)lo[1], (__bf16)lo[2], (__bf16)lo[3],
                               (__bf16)hg[0], (__bf16)hg[1], (__bf16)hg[2], (__bf16)hg[3]};
            #pragma unroll
            for (int am = 0; am < 4; ++am) acc[am] = mfma16(qf[am][s], kf, acc[am]);
        }
        if (l15 < 8) {
            #pragma unroll
            for (int am = 0; am < 4; ++am)
                #pragma unroll
                for (int j = 0; j < 4; ++j)
                    lpf[(w * 64 + am * 16 + hi * 4 + j) * 10 + l15] = acc[am][j];
        }
        LDS_BARRIER();

        // ---- online softmax: 8 threads per p-row, 1 token each ----
        float s0 = 0.f;
        #pragma unroll
        for (int sl = 0; sl < 8; ++sl) s0 += lpf[(sl * 64 + p_) * 10 + np_];
        s0 *= scale;
        float mt = s0;
        mt = fmaxf(mt, __shfl_xor(mt, 1));
        mt = fmaxf(mt, __shfl_xor(mt, 2));
        mt = fmaxf(mt, __shfl_xor(mt, 4));
        const float mo = mrun[p_];
        const float mn = fmaxf(mo, mt);
        const float e0 = __expf(s0 - mn);
        float lsum = e0;
        lsum += __shfl_xor(lsum, 1);
        lsum += __shfl_xor(lsum, 2);
        lsum += __shfl_xor(lsum, 4);
        pbuf[p_ * PSTRIDE + np_] = (__bf16)e0;
        if (np_ == 0) {
            const float f = __expf(mo - mn);   // == 1.0 exactly when mt <= mo
            lrun[p_] = lrun[p_] * f + lsum;
            mrun[p_] = mn;
            rsc[p_]  = f;
        }
        LDS_BARRIER();

        // ---- O-rescale (exact skip when no row's max grew) ----
        #pragma unroll
        for (int am = 0; am < 4; ++am) {
            float f[4];
            #pragma unroll
            for (int j = 0; j < 4; ++j) f[j] = rsc[am * 16 + hi * 4 + j];
            const bool nz = (f[0] != 1.f) | (f[1] != 1.f) | (f[2] != 1.f) | (f[3] != 1.f);
            if (__any(nz)) {
                #pragma unroll
                for (int df = 0; df < 6; ++df)
                    #pragma unroll
                    for (int j = 0; j < 4; ++j) O[am][df][j] *= f[j];
            }
        }

#if HAVE_K16
        // ---- PV via K=16 MFMA: k>=8 duplicates live rows x zero P ----
        s16x4 pf[4];
        #pragma unroll
        for (int am = 0; am < 4; ++am)
            pf[am] = *(const s16x4*)&pbuf[(am * 16 + l15) * PSTRIDE + hi * 4];
        #pragma unroll
        for (int df = 0; df < 6; ++df) {
            const int d_ = w * 96 + df * 16 + l15;
            s16x4 vfr;
            #pragma unroll
            for (int i = 0; i < 4; ++i) {
                const int k_ = (hi * 4 + i) & 7;
                vfr[i] = bf2s(vb[k_ * VROW + d_]);
            }
            #pragma unroll
            for (int am = 0; am < 4; ++am)
                O[am][df] = __builtin_amdgcn_mfma_f32_16x16x16bf16_1k(pf[am], vfr, O[am][df], 0, 0, 0);
        }
#else
        // ---- fallback: K=32 MFMA, k>=8 duplicates live rows x zero P ----
        bf16x8 pf[4];
        #pragma unroll
        for (int am = 0; am < 4; ++am)
            pf[am] = *(const bf16x8*)&pbuf[(am * 16 + l15) * PSTRIDE + hi * 8];
        #pragma unroll
        for (int df = 0; df < 6; ++df) {
            const int d_ = w * 96 + df * 16 + l15;
            float vf[8];
            #pragma unroll
            for (int i = 0; i < 8; ++i) {
                const int k_ = (hi * 8 + i) & 7;
                vf[i] = vb[k_ * VROW + d_];
            }
            const bf16x8 vfr = {(__bf16)vf[0], (__bf16)vf[1], (__bf16)vf[2], (__bf16)vf[3],
                                (__bf16)vf[4], (__bf16)vf[5], (__bf16)vf[6], (__bf16)vf[7]};
            #pragma unroll
            for (int am = 0; am < 4; ++am) O[am][df] = mfma16(pf[am], vfr, O[am][df]);
        }
#endif
        LDS_BARRIER();
    }

    // ---- epilogue: stats + unnormalized O to part (f16) ----
    if (t < 64) {
        const size_t si = ((size_t)b * 16 + sp) * 64 + t;
        statm[si] = mrun[t];
        statl[si] = lrun[t];
    }
    #pragma unroll
    for (int am = 0; am < 4; ++am)
        #pragma unroll
        for (int j = 0; j < 4; ++j) {
            const int p = am * 16 + hi * 4 + j;
            #pragma unroll
            for (int df = 0; df < 6; ++df) {
                const int d_ = w * 96 + df * 16 + l15;
                part[(((size_t)sp * BB + b) * PP + p) * DD + d_] = (_Float16)O[am][df][j];
            }
        }
}

// ---------------------------------------------------------------------------
// Combine: out[b,p,d] = sum_sp exp(m_sp - M) * part[sp,b,p,d] / D,
//          D = sum_c exp(m_c - M) * l_c.
// ---------------------------------------------------------------------------
__global__ __launch_bounds__(256) void k_combine(const _Float16* __restrict__ part,
                                                 const float* __restrict__ statm,
                                                 const float* __restrict__ statl,
                                                 float* __restrict__ out) {
    const size_t idx = (size_t)blockIdx.x * 256 + threadIdx.x;  // f32x4 units
    const size_t e = idx * 4;
    const int bp = (int)(e / DD);
    const int b = bp >> 6, p = bp & 63;

    float M = -1e30f;
    #pragma unroll
    for (int c = 0; c < 16; ++c) M = fmaxf(M, statm[((size_t)b * 16 + c) * 64 + p]);
    float Ee[16];
    float D = 0.f;
    #pragma unroll
    for (int c = 0; c < 16; ++c) {
        Ee[c] = __expf(statm[((size_t)b * 16 + c) * 64 + p] - M);
        D += Ee[c] * statl[((size_t)b * 16 + c) * 64 + p];
    }
    const float inv = 1.f / D;

    float4 v = {0.f, 0.f, 0.f, 0.f};
    #pragma unroll
    for (int c = 0; c < 16; ++c) {
        const f16x4 h = *(const f16x4*)&part[(size_t)c * ((size_t)BB * PP * DD) + e];
        v.x += Ee[c] * (float)h[0];
        v.y += Ee[c] * (float)h[1];
        v.z += Ee[c] * (float)h[2];
        v.w += Ee[c] * (float)h[3];
    }
    v.x *= inv; v.y *= inv; v.z *= inv; v.w *= inv;
    *(float4*)&out[e] = v;
}

extern "C" void kernel_launch(void* const* d_in, const int* in_sizes, int n_in,
                              void* d_out, int out_size, void* d_ws, size_t ws_size,
                              hipStream_t stream) {
    const float* x = (const float*)d_in[0];   // [16, 4096, 768]
    const float* q = (const float*)d_in[1];   // [16, 64, 768]
    float* out = (float*)d_out;               // [16, 64, 768]

    char* ws = (char*)d_ws;
    float*     statm = (float*)ws;                       // 64 KB [16][16][64]
    float*     statl = (float*)(ws + 65536);             // 64 KB
    _Float16*  part  = (_Float16*)(ws + 131072);         // 24 MB [16][16][64][768]

    hipLaunchKernelGGL(k_flash,   dim3(256), dim3(512), 0, stream, x, q, statm, statl, part);
    hipLaunchKernelGGL(k_combine, dim3(768), dim3(256), 0, stream, part, statm, statl, out);
}

// Round 12
// 64.288 us; speedup vs baseline: 1.3933x; 1.3933x over previous
//
#include <hip/hip_runtime.h>
#include <hip/hip_bf16.h>

// Shapes
#define BB 16
#define PP 64
#define NN 4096
#define DD 768
#define TT 16      // tokens per compute tile
#define NTILE 16   // tiles per 256-token chunk (32 half-tiles)
#define VROW 772   // padded LDS row stride (f32): 772 % 32 == 4 -> bank-spread rows
#define SLOT (8 * VROW)   // floats per half-tile slot (5-slot ring)

typedef __attribute__((ext_vector_type(4))) float f32x4;
typedef __attribute__((ext_vector_type(8))) __bf16 bf16x8;
typedef __attribute__((ext_vector_type(2))) __bf16 bf16x2;
typedef __attribute__((ext_vector_type(4))) short s16x4;
typedef __attribute__((ext_vector_type(4))) _Float16 f16x4;

#if __has_builtin(__builtin_amdgcn_mfma_f32_16x16x16bf16_1k)
#define HAVE_K16 1
#define PSTRIDE 20
#else
#define HAVE_K16 0
#define PSTRIDE 40
#endif

__device__ __forceinline__ f32x4 mfma16(bf16x8 a, bf16x8 b, f32x4 c) {
    return __builtin_amdgcn_mfma_f32_16x16x32_bf16(a, b, c, 0, 0, 0);
}

__device__ __forceinline__ void gl_lds(const float* g, float* l) {
    __builtin_amdgcn_global_load_lds(
        (const __attribute__((address_space(1))) void*)g,
        (__attribute__((address_space(3))) void*)l, 16, 0, 0);
}

__device__ __forceinline__ short bf2s(float f) {
    __bf16 h = (__bf16)f;
    return *(short*)&h;
}

#define S_WAITCNT_VM(N) asm volatile("s_waitcnt vmcnt(" #N ")" ::: "memory")
#define BARRIER() do { __builtin_amdgcn_s_barrier(); asm volatile("" ::: "memory"); } while (0)
// LDS-only barrier: drains ds ops, NOT vmcnt (DMA prefetch stays in flight).
#define LDS_BARRIER() do { asm volatile("s_waitcnt lgkmcnt(0)" ::: "memory"); \
                           __builtin_amdgcn_s_barrier(); \
                           __builtin_amdgcn_sched_barrier(0); } while (0)

// LDS layout (bytes):
//   [0,     123520)  vstage[5][8][772] f32  (half-tile ring, 3 halves in flight)
//   [123520,160384)  lpf[8][64][18] f32     (QK^T kd-slice partials)
//   [160384,162944)  pbuf[64][PSTRIDE] bf16 (P tile)
//   [162944,163712)  mrun/lrun/rsc [64] f32 each
#define SM_BYTES 163712

// ---------------------------------------------------------------------------
// Flash: per (b, 256-token chunk), stream 16 tiles of 16 tokens x 768 d (f32)
// through a 5-half-slot LDS ring ONCE; per tile: QK^T -> online softmax -> PV
// into reg-resident O. grid 256 = 16 b x 16 chunks; block 512 (8 waves).
// ---------------------------------------------------------------------------
__global__ __launch_bounds__(512, 2) void k_flash(const float* __restrict__ x,
                                                  const float* __restrict__ q,
                                                  float* __restrict__ statm,
                                                  float* __restrict__ statl,
                                                  _Float16* __restrict__ part) {
    const int b  = blockIdx.x >> 4;
    const int sp = blockIdx.x & 15;
    const int n0 = sp * 256;

    __shared__ __align__(16) char smem[SM_BYTES];
    float*  vst  = (float*)smem;
    float*  lpf  = (float*)(smem + 123520);
    __bf16* pbuf = (__bf16*)(smem + 160384);
    float*  mrun = (float*)(smem + 162944);
    float*  lrun = (float*)(smem + 163200);
    float*  rsc  = (float*)(smem + 163456);

    const int t = threadIdx.x;
    const int w = t >> 6, lane = t & 63;
    const int l15 = lane & 15, hi = lane >> 4;

    const size_t xbase = (size_t)b * NN + n0;
    const size_t qbase = (size_t)b * PP;

    // ---- Q-fragment preload: wave w owns kd-slice [w*96, w*96+96) ----
    bf16x8 qf[4][3];
    #pragma unroll
    for (int am = 0; am < 4; ++am)
        #pragma unroll
        for (int s = 0; s < 3; ++s) {
            const size_t off = (qbase + am * 16 + l15) * DD + w * 96 + s * 32 + hi * 8;
            const float4 a = *(const float4*)&q[off];
            const float4 c = *(const float4*)&q[off + 4];
            qf[am][s] = (bf16x8){(__bf16)a.x, (__bf16)a.y, (__bf16)a.z, (__bf16)a.w,
                                 (__bf16)c.x, (__bf16)c.y, (__bf16)c.z, (__bf16)c.w};
        }

#if !HAVE_K16
    // fallback path: zero P pad region (k >= 16 multiplies real data)
    for (int i = t; i < 64 * PSTRIDE / 2; i += 512) ((unsigned*)pbuf)[i] = 0;
#endif
    if (t < 64) { mrun[t] = -1e30f; lrun[t] = 0.f; }

    // O accumulator: wave w owns d-slice [w*96, w*96+96): 4 p-frags x 6 d-frags.
    f32x4 O[4][6] = {};

    // Stage half-tile h (8 rows x 768 f32 = 24 KB) into ring slot h%5.
    // 3 issues/wave: wave w covers row w... (8 waves = 8 rows), third i_.
#define STAGE_H(h) do {                                                       \
        float* vb_ = vst + ((h) % 5) * SLOT;                                  \
        _Pragma("unroll")                                                     \
        for (int i_ = 0; i_ < 3; ++i_) {                                      \
            gl_lds(&x[(xbase + (size_t)(h) * 8 + w) * DD + i_ * 256 + lane * 4], \
                   vb_ + w * VROW + i_ * 256);                                \
        }                                                                     \
    } while (0)

    STAGE_H(0); STAGE_H(1); STAGE_H(2);

    const float scale = 0.036084391824351615f;  // 768^-0.5
    const int p_  = t >> 3;      // softmax row (0..63)
    const int np_ = t & 7;       // softmax token-pair (0..7)

    for (int tile = 0; tile < NTILE; ++tile) {
        if (tile < NTILE - 2) {
            STAGE_H(2 * tile + 3); STAGE_H(2 * tile + 4);
            S_WAITCNT_VM(9);          // 3 half-tiles (72 KB) stay in flight
        } else if (tile == NTILE - 2) {
            STAGE_H(31);
            S_WAITCNT_VM(6);
        } else {
            S_WAITCNT_VM(0);
        }
        BARRIER();
        const float* vbl = vst + ((2 * tile)     % 5) * SLOT;   // rows 0..7
        const float* vbh = vst + ((2 * tile + 1) % 5) * SLOT;   // rows 8..15
        const float* rowq = (l15 < 8) ? (vbl + l15 * VROW) : (vbh + (l15 - 8) * VROW);

        // ---- QK^T: wave w: kd in {w*96, +32, +64}, all 4 p-frags ----
        f32x4 acc[4] = {};
        #pragma unroll
        for (int s = 0; s < 3; ++s) {
            const int g0 = w * 24 + s * 8 + hi * 2;
            const float* kp = rowq + g0 * 4;
            const f32x4 lo = *(const f32x4*)kp;
            const f32x4 hg = *(const f32x4*)(kp + 4);
            const bf16x8 kf = {(__bf16)lo[0], (__bf16)lo[1], (__bf16)lo[2], (__bf16)lo[3],
                               (__bf16)hg[0], (__bf16)hg[1], (__bf16)hg[2], (__bf16)hg[3]};
            #pragma unroll
            for (int am = 0; am < 4; ++am) acc[am] = mfma16(qf[am][s], kf, acc[am]);
        }
        #pragma unroll
        for (int am = 0; am < 4; ++am)
            #pragma unroll
            for (int j = 0; j < 4; ++j)
                lpf[(w * 64 + am * 16 + hi * 4 + j) * 18 + l15] = acc[am][j];
        LDS_BARRIER();

        // ---- online softmax: 8 threads per p-row, 2 tokens each ----
        float s0 = 0.f, s1 = 0.f;
        #pragma unroll
        for (int sl = 0; sl < 8; ++sl) {
            const float2 v2 = *(const float2*)&lpf[(sl * 64 + p_) * 18 + 2 * np_];
            s0 += v2.x; s1 += v2.y;
        }
        s0 *= scale; s1 *= scale;
        float mt = fmaxf(s0, s1);
        mt = fmaxf(mt, __shfl_xor(mt, 1));
        mt = fmaxf(mt, __shfl_xor(mt, 2));
        mt = fmaxf(mt, __shfl_xor(mt, 4));
        const float mo = mrun[p_];
        const float mn = fmaxf(mo, mt);
        const float e0 = __expf(s0 - mn), e1 = __expf(s1 - mn);
        float lsum = e0 + e1;
        lsum += __shfl_xor(lsum, 1);
        lsum += __shfl_xor(lsum, 2);
        lsum += __shfl_xor(lsum, 4);
        *(bf16x2*)&pbuf[p_ * PSTRIDE + 2 * np_] = (bf16x2){(__bf16)e0, (__bf16)e1};
        if (np_ == 0) {
            const float f = __expf(mo - mn);   // == 1.0 exactly when mt <= mo
            lrun[p_] = lrun[p_] * f + lsum;
            mrun[p_] = mn;
            rsc[p_]  = f;
        }
        LDS_BARRIER();

        // ---- O-rescale (exact skip when no row's max grew) ----
        #pragma unroll
        for (int am = 0; am < 4; ++am) {
            float f[4];
            #pragma unroll
            for (int j = 0; j < 4; ++j) f[j] = rsc[am * 16 + hi * 4 + j];
            const bool nz = (f[0] != 1.f) | (f[1] != 1.f) | (f[2] != 1.f) | (f[3] != 1.f);
            if (__any(nz)) {
                #pragma unroll
                for (int df = 0; df < 6; ++df)
                    #pragma unroll
                    for (int j = 0; j < 4; ++j) O[am][df][j] *= f[j];
            }
        }

#if HAVE_K16
        // ---- PV via K=16 MFMA: k = hi*4+i covers 0..15, all live ----
        // Row-half select depends only on hi (hi<2 -> rows 0..7).
        const float* pvb = (hi < 2) ? (vbl + (hi * 4) * VROW)
                                    : (vbh + (hi * 4 - 8) * VROW);
        s16x4 pf[4];
        #pragma unroll
        for (int am = 0; am < 4; ++am)
            pf[am] = *(const s16x4*)&pbuf[(am * 16 + l15) * PSTRIDE + hi * 4];
        #pragma unroll
        for (int df = 0; df < 6; ++df) {
            const int d_ = w * 96 + df * 16 + l15;
            const float* pvd = pvb + d_;
            s16x4 vfr;
            #pragma unroll
            for (int i = 0; i < 4; ++i) vfr[i] = bf2s(pvd[i * VROW]);
            #pragma unroll
            for (int am = 0; am < 4; ++am)
                O[am][df] = __builtin_amdgcn_mfma_f32_16x16x16bf16_1k(pf[am], vfr, O[am][df], 0, 0, 0);
        }
#else
        // ---- fallback: K=32 MFMA, k = (hi*8+i)&15; pad k>=16 is zero P ----
        // (hi even -> rows 0..7, hi odd -> rows 8..15)
        const float* pvb = (hi & 1) ? vbh : vbl;
        bf16x8 pf[4];
        #pragma unroll
        for (int am = 0; am < 4; ++am)
            pf[am] = *(const bf16x8*)&pbuf[(am * 16 + l15) * PSTRIDE + hi * 8];
        #pragma unroll
        for (int df = 0; df < 6; ++df) {
            const int d_ = w * 96 + df * 16 + l15;
            const float* pvd = pvb + d_;
            float vf[8];
            #pragma unroll
            for (int i = 0; i < 8; ++i) vf[i] = pvd[i * VROW];
            const bf16x8 vfr = {(__bf16)vf[0], (__bf16)vf[1], (__bf16)vf[2], (__bf16)vf[3],
                                (__bf16)vf[4], (__bf16)vf[5], (__bf16)vf[6], (__bf16)vf[7]};
            #pragma unroll
            for (int am = 0; am < 4; ++am) O[am][df] = mfma16(pf[am], vfr, O[am][df]);
        }
#endif
        LDS_BARRIER();
    }

    // ---- epilogue: stats + unnormalized O to part (f16) ----
    if (t < 64) {
        const size_t si = ((size_t)b * 16 + sp) * 64 + t;
        statm[si] = mrun[t];
        statl[si] = lrun[t];
    }
    #pragma unroll
    for (int am = 0; am < 4; ++am)
        #pragma unroll
        for (int j = 0; j < 4; ++j) {
            const int p = am * 16 + hi * 4 + j;
            #pragma unroll
            for (int df = 0; df < 6; ++df) {
                const int d_ = w * 96 + df * 16 + l15;
                part[(((size_t)sp * BB + b) * PP + p) * DD + d_] = (_Float16)O[am][df][j];
            }
        }
}

// ---------------------------------------------------------------------------
// Combine: out[b,p,d] = sum_sp exp(m_sp - M) * part[sp,b,p,d] / D,
//          D = sum_c exp(m_c - M) * l_c.
// ---------------------------------------------------------------------------
__global__ __launch_bounds__(256) void k_combine(const _Float16* __restrict__ part,
                                                 const float* __restrict__ statm,
                                                 const float* __restrict__ statl,
                                                 float* __restrict__ out) {
    const size_t idx = (size_t)blockIdx.x * 256 + threadIdx.x;  // f32x4 units
    const size_t e = idx * 4;
    const int bp = (int)(e / DD);
    const int b = bp >> 6, p = bp & 63;

    float M = -1e30f;
    #pragma unroll
    for (int c = 0; c < 16; ++c) M = fmaxf(M, statm[((size_t)b * 16 + c) * 64 + p]);
    float Ee[16];
    float D = 0.f;
    #pragma unroll
    for (int c = 0; c < 16; ++c) {
        Ee[c] = __expf(statm[((size_t)b * 16 + c) * 64 + p] - M);
        D += Ee[c] * statl[((size_t)b * 16 + c) * 64 + p];
    }
    const float inv = 1.f / D;

    float4 v = {0.f, 0.f, 0.f, 0.f};
    #pragma unroll
    for (int c = 0; c < 16; ++c) {
        const f16x4 h = *(const f16x4*)&part[(size_t)c * ((size_t)BB * PP * DD) + e];
        v.x += Ee[c] * (float)h[0];
        v.y += Ee[c] * (float)h[1];
        v.z += Ee[c] * (float)h[2];
        v.w += Ee[c] * (float)h[3];
    }
    v.x *= inv; v.y *= inv; v.z *= inv; v.w *= inv;
    *(float4*)&out[e] = v;
}

extern "C" void kernel_launch(void* const* d_in, const int* in_sizes, int n_in,
                              void* d_out, int out_size, void* d_ws, size_t ws_size,
                              hipStream_t stream) {
    const float* x = (const float*)d_in[0];   // [16, 4096, 768]
    const float* q = (const float*)d_in[1];   // [16, 64, 768]
    float* out = (float*)d_out;               // [16, 64, 768]

    char* ws = (char*)d_ws;
    float*     statm = (float*)ws;                       // 64 KB [16][16][64]
    float*     statl = (float*)(ws + 65536);             // 64 KB
    _Float16*  part  = (_Float16*)(ws + 131072);         // 24 MB [16][16][64][768]

    hipLaunchKernelGGL(k_flash,   dim3(256), dim3(512), 0, stream, x, q, statm, statl, part);
    hipLaunchKernelGGL(k_combine, dim3(768), dim3(256), 0, stream, part, statm, statl, out);
}

// Round 13
// 62.690 us; speedup vs baseline: 1.4288x; 1.0255x over previous
//
#include <hip/hip_runtime.h>
#include <hip/hip_bf16.h>

// Shapes
#define BB 16
#define PP 64
#define NN 4096
#define DD 768
#define TT 16      // tokens per tile
#define NTILE 16   // tiles per 256-token chunk

typedef __attribute__((ext_vector_type(4))) float f32x4;
typedef __attribute__((ext_vector_type(8))) __bf16 bf16x8;
typedef __attribute__((ext_vector_type(2))) __bf16 bf16x2;
typedef __attribute__((ext_vector_type(4))) short s16x4;
typedef __attribute__((ext_vector_type(4))) _Float16 f16x4;

#if __has_builtin(__builtin_amdgcn_mfma_f32_16x16x16bf16_1k)
#define HAVE_K16 1
#else
#define HAVE_K16 0
#endif
#define PSTRIDE 40   // bf16 elems per pbuf row (worst-case alloc; K16 uses 0..15)

__device__ __forceinline__ f32x4 mfma16(bf16x8 a, bf16x8 b, f32x4 c) {
    return __builtin_amdgcn_mfma_f32_16x16x32_bf16(a, b, c, 0, 0, 0);
}

__device__ __forceinline__ void gl_lds(const float* g, float* l) {
    __builtin_amdgcn_global_load_lds(
        (const __attribute__((address_space(1))) void*)g,
        (__attribute__((address_space(3))) void*)l, 16, 0, 0);
}

__device__ __forceinline__ short bf2s(float f) {
    __bf16 h = (__bf16)f;
    return *(short*)&h;
}

#define S_WAITCNT_VM(N) asm volatile("s_waitcnt vmcnt(" #N ")" ::: "memory")
// LDS-only barrier: drains ds ops, NOT vmcnt (DMA prefetch stays in flight).
#define LDS_BARRIER() do { asm volatile("s_waitcnt lgkmcnt(0)" ::: "memory"); \
                           __builtin_amdgcn_s_barrier(); \
                           __builtin_amdgcn_sched_barrier(0); } while (0)

// LDS (bytes):
//   [0,      98304)  vst[2 buf][8 waves][16 rows][24 granules x 16B] f32
//                    wave-PRIVATE V slices (96 d columns each), octet-XOR swz
//   [98304, 135168)  lpf[8][64][18] f32  (QK^T kd-slice partials, wave-private rows)
//   [135168,140288)  pbuf[64][PSTRIDE] bf16
//   [140288,141056)  mrun/lrun/rsc [64] f32 each
#define SM_BYTES 141056

// ---------------------------------------------------------------------------
// Flash, wave-local staging: per (b, 256-token chunk), stream 16 tiles of
// 16 tokens x 768 d. Each wave DMAs its own 96-d column slice into private
// LDS; QK/PV read only own slice (own-vmcnt guarded, NO barrier). Only the
// softmax P-path crosses waves (2 LDS barriers/tile).
// grid 256 = 16 b x 16 chunks; block 512 (8 waves).
// ---------------------------------------------------------------------------
__global__ __launch_bounds__(512, 2) void k_flash(const float* __restrict__ x,
                                                  const float* __restrict__ q,
                                                  float* __restrict__ statm,
                                                  float* __restrict__ statl,
                                                  _Float16* __restrict__ part) {
    const int b  = blockIdx.x >> 4;
    const int sp = blockIdx.x & 15;
    const int n0 = sp * 256;

    __shared__ __align__(16) char smem[SM_BYTES];
    float*  vst  = (float*)smem;
    float*  lpf  = (float*)(smem + 98304);
    __bf16* pbuf = (__bf16*)(smem + 135168);
    float*  mrun = (float*)(smem + 140288);
    float*  lrun = (float*)(smem + 140544);
    float*  rsc  = (float*)(smem + 140800);

    const int t = threadIdx.x;
    const int w = t >> 6, lane = t & 63;
    const int l15 = lane & 15, hi = lane >> 4;

    const float* xp = x + ((size_t)b * NN + n0) * DD;
    const size_t qbase = (size_t)b * PP;

    // ---- Q-fragment preload: wave w owns kd-slice [w*96, w*96+96) ----
    bf16x8 qf[4][3];
    #pragma unroll
    for (int am = 0; am < 4; ++am)
        #pragma unroll
        for (int s = 0; s < 3; ++s) {
            const size_t off = (qbase + am * 16 + l15) * DD + w * 96 + s * 32 + hi * 8;
            const float4 a = *(const float4*)&q[off];
            const float4 c = *(const float4*)&q[off + 4];
            qf[am][s] = (bf16x8){(__bf16)a.x, (__bf16)a.y, (__bf16)a.z, (__bf16)a.w,
                                 (__bf16)c.x, (__bf16)c.y, (__bf16)c.z, (__bf16)c.w};
        }

#if !HAVE_K16
    for (int i = t; i < 64 * PSTRIDE / 2; i += 512) ((unsigned*)pbuf)[i] = 0;
#endif
    if (t < 64) { mrun[t] = -1e30f; lrun[t] = 0.f; }
#if !HAVE_K16
    __syncthreads();   // pbuf zeros visible before first PV
#endif

    // O accumulator: wave w owns d-slice [w*96, w*96+96): 4 p-frags x 6 d-frags.
    f32x4 O[4][6] = {};

    // ---- staging precompute: 6 issues/wave cover [16 rows][24 granules].
    // dest granule idx d = i*64+lane (linear, 16B-aligned, wave-uniform base);
    // source granule g = octet-XOR swizzle of slot by row (bijective in 0..23).
    int srcF[6];
    #pragma unroll
    for (int i = 0; i < 6; ++i) {
        const int d = i * 64 + lane;
        const int row  = d / 24;
        const int slot = d - row * 24;
        const int g = (slot & ~7) | ((slot & 7) ^ (row & 7));
        srcF[i] = row * DD + w * 96 + g * 4;
    }

#define STAGE(bufi, tile) do {                                                \
        float* vb_ = vst + ((bufi) * 8 + w) * 1536;                           \
        const float* sp_ = xp + (size_t)(tile) * (TT * DD);                   \
        _Pragma("unroll")                                                     \
        for (int i_ = 0; i_ < 6; ++i_)                                        \
            gl_lds(sp_ + srcF[i_], vb_ + i_ * 256);                           \
    } while (0)

    STAGE(0, 0);

    const float scale = 0.036084391824351615f;  // 768^-0.5
    const int p_  = t >> 3;      // softmax row (0..63)
    const int np_ = t & 7;       // softmax token-pair (0..7)

    for (int tile = 0; tile < NTILE; ++tile) {
        // own ds ops drained before re-issuing into the buffer PV just read
        asm volatile("s_waitcnt lgkmcnt(0)" ::: "memory");
        if (tile < NTILE - 1) { STAGE((tile + 1) & 1, tile + 1); S_WAITCNT_VM(6); }
        else                  { S_WAITCNT_VM(0); }
        __builtin_amdgcn_sched_barrier(0);

        const float* reg = vst + ((tile & 1) * 8 + w) * 1536;   // own slice

        // ---- QK^T from OWN slice (no barrier needed) ----
        f32x4 acc[4] = {};
        #pragma unroll
        for (int s = 0; s < 3; ++s) {
            const int ga = s * 8 + hi * 2, gb = ga + 1;
            const int sa = (ga & ~7) | ((ga & 7) ^ (l15 & 7));
            const int sb = (gb & ~7) | ((gb & 7) ^ (l15 & 7));
            const f32x4 lo = *(const f32x4*)(reg + l15 * 96 + sa * 4);
            const f32x4 hg = *(const f32x4*)(reg + l15 * 96 + sb * 4);
            const bf16x8 kf = {(__bf16)lo[0], (__bf16)lo[1], (__bf16)lo[2], (__bf16)lo[3],
                               (__bf16)hg[0], (__bf16)hg[1], (__bf16)hg[2], (__bf16)hg[3]};
            #pragma unroll
            for (int am = 0; am < 4; ++am) acc[am] = mfma16(qf[am][s], kf, acc[am]);
        }
        // wave-private lpf rows; other waves' softmax(t) finished before B2(t-1)
        #pragma unroll
        for (int am = 0; am < 4; ++am)
            #pragma unroll
            for (int j = 0; j < 4; ++j)
                lpf[(w * 64 + am * 16 + hi * 4 + j) * 18 + l15] = acc[am][j];
        LDS_BARRIER();   // B1: all lpf written

        // ---- online softmax: 8 threads per p-row, 2 tokens each ----
        float s0 = 0.f, s1 = 0.f;
        #pragma unroll
        for (int sl = 0; sl < 8; ++sl) {
            const float2 v2 = *(const float2*)&lpf[(sl * 64 + p_) * 18 + 2 * np_];
            s0 += v2.x; s1 += v2.y;
        }
        s0 *= scale; s1 *= scale;
        float mt = fmaxf(s0, s1);
        mt = fmaxf(mt, __shfl_xor(mt, 1));
        mt = fmaxf(mt, __shfl_xor(mt, 2));
        mt = fmaxf(mt, __shfl_xor(mt, 4));
        const float mo = mrun[p_];
        const float mn = fmaxf(mo, mt);
        const float e0 = __expf(s0 - mn), e1 = __expf(s1 - mn);
        float lsum = e0 + e1;
        lsum += __shfl_xor(lsum, 1);
        lsum += __shfl_xor(lsum, 2);
        lsum += __shfl_xor(lsum, 4);
        *(bf16x2*)&pbuf[p_ * PSTRIDE + 2 * np_] = (bf16x2){(__bf16)e0, (__bf16)e1};
        if (np_ == 0) {
            const float f = __expf(mo - mn);   // == 1.0 exactly when mt <= mo
            lrun[p_] = lrun[p_] * f + lsum;
            mrun[p_] = mn;
            rsc[p_]  = f;
        }
        LDS_BARRIER();   // B2: pbuf/rsc ready

        // ---- O-rescale (exact skip when no row's max grew) ----
        #pragma unroll
        for (int am = 0; am < 4; ++am) {
            float f[4];
            #pragma unroll
            for (int j = 0; j < 4; ++j) f[j] = rsc[am * 16 + hi * 4 + j];
            const bool nz = (f[0] != 1.f) | (f[1] != 1.f) | (f[2] != 1.f) | (f[3] != 1.f);
            if (__any(nz)) {
                #pragma unroll
                for (int df = 0; df < 6; ++df)
                    #pragma unroll
                    for (int j = 0; j < 4; ++j) O[am][df][j] *= f[j];
            }
        }

#if HAVE_K16
        // ---- PV via K=16 MFMA from OWN slice ----
        s16x4 pf[4];
        #pragma unroll
        for (int am = 0; am < 4; ++am)
            pf[am] = *(const s16x4*)&pbuf[(am * 16 + l15) * PSTRIDE + hi * 4];
        #pragma unroll
        for (int df = 0; df < 6; ++df) {
            const int dl = df * 16 + l15;          // local d col 0..95
            const int g = dl >> 2, sub = dl & 3;
            s16x4 vfr;
            #pragma unroll
            for (int i = 0; i < 4; ++i) {
                const int r = hi * 4 + i;
                const int sl2 = (g & ~7) | ((g & 7) ^ (r & 7));
                vfr[i] = bf2s(reg[r * 96 + sl2 * 4 + sub]);
            }
            #pragma unroll
            for (int am = 0; am < 4; ++am)
                O[am][df] = __builtin_amdgcn_mfma_f32_16x16x16bf16_1k(pf[am], vfr, O[am][df], 0, 0, 0);
        }
#else
        // ---- fallback: K=32 MFMA, pad k>=16 multiplies zero P ----
        bf16x8 pf[4];
        #pragma unroll
        for (int am = 0; am < 4; ++am)
            pf[am] = *(const bf16x8*)&pbuf[(am * 16 + l15) * PSTRIDE + hi * 8];
        #pragma unroll
        for (int df = 0; df < 6; ++df) {
            const int dl = df * 16 + l15;
            const int g = dl >> 2, sub = dl & 3;
            float vf[8];
            #pragma unroll
            for (int i = 0; i < 8; ++i) {
                const int r = (hi * 8 + i) & 15;
                const int sl2 = (g & ~7) | ((g & 7) ^ (r & 7));
                vf[i] = reg[r * 96 + sl2 * 4 + sub];
            }
            const bf16x8 vfr = {(__bf16)vf[0], (__bf16)vf[1], (__bf16)vf[2], (__bf16)vf[3],
                                (__bf16)vf[4], (__bf16)vf[5], (__bf16)vf[6], (__bf16)vf[7]};
            #pragma unroll
            for (int am = 0; am < 4; ++am) O[am][df] = mfma16(pf[am], vfr, O[am][df]);
        }
#endif
        // no end barrier: next tile's STAGE targets the other buffer; lpf(t+1)
        // writes are wave-private rows; pbuf(t+1) written only after B1(t+1).
    }

    // ---- epilogue: stats + unnormalized O to part (f16) ----
    if (t < 64) {
        const size_t si = ((size_t)b * 16 + sp) * 64 + t;
        statm[si] = mrun[t];
        statl[si] = lrun[t];
    }
    #pragma unroll
    for (int am = 0; am < 4; ++am)
        #pragma unroll
        for (int j = 0; j < 4; ++j) {
            const int p = am * 16 + hi * 4 + j;
            #pragma unroll
            for (int df = 0; df < 6; ++df) {
                const int d_ = w * 96 + df * 16 + l15;
                part[(((size_t)sp * BB + b) * PP + p) * DD + d_] = (_Float16)O[am][df][j];
            }
        }
}

// ---------------------------------------------------------------------------
// Combine: out[b,p,d] = sum_sp exp(m_sp - M) * part[sp,b,p,d] / D,
//          D = sum_c exp(m_c - M) * l_c.
// ---------------------------------------------------------------------------
__global__ __launch_bounds__(256) void k_combine(const _Float16* __restrict__ part,
                                                 const float* __restrict__ statm,
                                                 const float* __restrict__ statl,
                                                 float* __restrict__ out) {
    const size_t idx = (size_t)blockIdx.x * 256 + threadIdx.x;  // f32x4 units
    const size_t e = idx * 4;
    const int bp = (int)(e / DD);
    const int b = bp >> 6, p = bp & 63;

    float M = -1e30f;
    #pragma unroll
    for (int c = 0; c < 16; ++c) M = fmaxf(M, statm[((size_t)b * 16 + c) * 64 + p]);
    float Ee[16];
    float D = 0.f;
    #pragma unroll
    for (int c = 0; c < 16; ++c) {
        Ee[c] = __expf(statm[((size_t)b * 16 + c) * 64 + p] - M);
        D += Ee[c] * statl[((size_t)b * 16 + c) * 64 + p];
    }
    const float inv = 1.f / D;

    float4 v = {0.f, 0.f, 0.f, 0.f};
    #pragma unroll
    for (int c = 0; c < 16; ++c) {
        const f16x4 h = *(const f16x4*)&part[(size_t)c * ((size_t)BB * PP * DD) + e];
        v.x += Ee[c] * (float)h[0];
        v.y += Ee[c] * (float)h[1];
        v.z += Ee[c] * (float)h[2];
        v.w += Ee[c] * (float)h[3];
    }
    v.x *= inv; v.y *= inv; v.z *= inv; v.w *= inv;
    *(float4*)&out[e] = v;
}

extern "C" void kernel_launch(void* const* d_in, const int* in_sizes, int n_in,
                              void* d_out, int out_size, void* d_ws, size_t ws_size,
                              hipStream_t stream) {
    const float* x = (const float*)d_in[0];   // [16, 4096, 768]
    const float* q = (const float*)d_in[1];   // [16, 64, 768]
    float* out = (float*)d_out;               // [16, 64, 768]

    char* ws = (char*)d_ws;
    float*     statm = (float*)ws;                       // 64 KB [16][16][64]
    float*     statl = (float*)(ws + 65536);             // 64 KB
    _Float16*  part  = (_Float16*)(ws + 131072);         // 24 MB [16][16][64][768]

    hipLaunchKernelGGL(k_flash,   dim3(256), dim3(512), 0, stream, x, q, statm, statl, part);
    hipLaunchKernelGGL(k_combine, dim3(768), dim3(256), 0, stream, part, statm, statl, out);
}